// Round 6
// baseline (367.481 us; speedup 1.0000x reference)
//
#include <hip/hip_runtime.h>
#include <hip/hip_fp16.h>
#include <math.h>

#define L_SIG 65537
#define NH    65536     // half-size complex FFT length (NFFT/2)
#define NSIG  256
#define PI_F  3.14159265358979323846f

struct alignas(8) c32 { float x, y; };   // 8B-aligned -> LDS ds_*_b64
typedef __half2 h2;                      // NOTE: h2 = 4 BYTES; float4 = 4 h2
__device__ __forceinline__ c32 mkc(float a, float b){ c32 r; r.x=a; r.y=b; return r; }
__device__ __forceinline__ c32 cadd(c32 a, c32 b){ return mkc(a.x+b.x, a.y+b.y); }
__device__ __forceinline__ c32 csub(c32 a, c32 b){ return mkc(a.x-b.x, a.y-b.y); }
__device__ __forceinline__ c32 cmul(c32 a, c32 b){ return mkc(a.x*b.x - a.y*b.y, a.x*b.y + a.y*b.x); }
__device__ __forceinline__ h2  c2h(c32 a){ return __floats2half2_rn(a.x, a.y); }
__device__ __forceinline__ c32 h2c(h2 a){ float2 f = __half22float2(a); return mkc(f.x, f.y); }

// ---------------- 16-point FFT in registers (radix-4 x 2) ------------------
template<int S>
__device__ __forceinline__ void fft16(c32 v[16]) {
  constexpr float C16[16] = {
    1.0f, 0.9238795325112867f, 0.7071067811865476f, 0.3826834323650898f,
    0.0f,-0.3826834323650898f,-0.7071067811865476f,-0.9238795325112867f,
   -1.0f,-0.9238795325112867f,-0.7071067811865476f,-0.3826834323650898f,
    0.0f, 0.3826834323650898f, 0.7071067811865476f, 0.9238795325112867f };
  constexpr float S16[16] = {
    0.0f, 0.3826834323650898f, 0.7071067811865476f, 0.9238795325112867f,
    1.0f, 0.9238795325112867f, 0.7071067811865476f, 0.3826834323650898f,
    0.0f,-0.3826834323650898f,-0.7071067811865476f,-0.9238795325112867f,
   -1.0f,-0.9238795325112867f,-0.7071067811865476f,-0.3826834323650898f };
  c32 s[16];
  #pragma unroll
  for (int b0 = 0; b0 < 4; ++b0) {
    c32 x0=v[b0], x1=v[b0+4], x2=v[b0+8], x3=v[b0+12];
    c32 u0=cadd(x0,x2), u1=csub(x0,x2), u2=cadd(x1,x3), u3=csub(x1,x3);
    c32 iu3 = mkc(-u3.y, u3.x);
    c32 yy[4];
    yy[0]=cadd(u0,u2); yy[2]=csub(u0,u2);
    if (S < 0) { yy[1]=csub(u1,iu3); yy[3]=cadd(u1,iu3); }
    else       { yy[1]=cadd(u1,iu3); yy[3]=csub(u1,iu3); }
    #pragma unroll
    for (int c0 = 0; c0 < 4; ++c0) {
      const int p = (b0*c0) & 15;
      c32 w = mkc(C16[p], (S<0) ? -S16[p] : S16[p]);
      s[c0*4 + b0] = cmul(yy[c0], w);
    }
  }
  #pragma unroll
  for (int c0 = 0; c0 < 4; ++c0) {
    c32 x0=s[c0*4+0], x1=s[c0*4+1], x2=s[c0*4+2], x3=s[c0*4+3];
    c32 u0=cadd(x0,x2), u1=csub(x0,x2), u2=cadd(x1,x3), u3=csub(x1,x3);
    c32 iu3 = mkc(-u3.y, u3.x);
    c32 yy[4];
    yy[0]=cadd(u0,u2); yy[2]=csub(u0,u2);
    if (S < 0) { yy[1]=csub(u1,iu3); yy[3]=cadd(u1,iu3); }
    else       { yy[1]=cadd(u1,iu3); yy[3]=csub(u1,iu3); }
    v[c0+0]=yy[0]; v[c0+4]=yy[1]; v[c0+8]=yy[2]; v[c0+12]=yy[3];
  }
}

// ------------- 256-pt FFT, 16-thread team, 16 KB two-phase transpose ------
template<int S>
__device__ __forceinline__ void fft256_team(c32 v[16], int r, int t, c32* sc) {
  fft16<S>(v);
  float ang = (float)S * (2.0f*PI_F/256.0f) * (float)r;
  c32 st; __sincosf(ang, &st.y, &st.x);
  c32 w = st;
  #pragma unroll
  for (int c = 1; c < 16; ++c) { v[c] = cmul(v[c], w); w = cmul(w, st); }
  int p  = r*8 + (t & 7);
  int fr = (r & 1) << 3;
  __syncthreads();
  if (t < 8) {
    #pragma unroll
    for (int c = 0; c < 16; ++c)
      sc[c*128 + (p ^ ((c & 1) << 3))] = v[c];
  }
  __syncthreads();
  if (t < 8) {
    #pragma unroll
    for (int a = 0; a < 16; ++a)
      v[a] = sc[r*128 + ((a*8 + (t & 7)) ^ fr)];
  }
  __syncthreads();
  if (t >= 8) {
    #pragma unroll
    for (int c = 0; c < 16; ++c)
      sc[c*128 + (p ^ ((c & 1) << 3))] = v[c];
  }
  __syncthreads();
  if (t >= 8) {
    #pragma unroll
    for (int a = 0; a < 16; ++a)
      v[a] = sc[r*128 + ((a*8 + (t & 7)) ^ fr)];
  }
  fft16<S>(v);
}

// ---------------- prep A: pm partial sums (md-separable) -------------------
__global__ __launch_bounds__(256) void k_pm(const float* __restrict__ hp,
                                            float* __restrict__ pm_part) {
  __shared__ float r0[256], r1[256];
  int t = threadIdx.x, b = blockIdx.x;
  int gid = b*256 + t;
  float s0 = 0.f, s1 = 0.f;
  for (int tt = gid; tt < 65537; tt += 16384) {
    int ci = (tt * 8) / 65537;
    float cs = hp[ci*4+0] + hp[ci*4+1] + hp[ci*4+2] + hp[ci*4+3];
    float ang = (6.2831853071795864769f * (float)tt) / 65537.0f;
    s0 += cs;
    s1 += cs * sinf(ang);
  }
  r0[t] = s0; r1[t] = s1;
  __syncthreads();
  for (int s = 128; s > 0; s >>= 1) {
    if (t < s) { r0[t] += r0[t+s]; r1[t] += r1[t+s]; }
    __syncthreads();
  }
  if (t == 0) { pm_part[2*b] = r0[0]; pm_part[2*b+1] = r1[0]; }
}

// ---------------- prep B: MLP md, final pm, spectral line table ------------
__global__ __launch_bounds__(256) void k_prep2(const float* __restrict__ b1,
    const float* __restrict__ W2, const float* __restrict__ b2,
    const float* __restrict__ W3, const float* __restrict__ b3,
    const float* __restrict__ fw, const float* __restrict__ pm_part,
    float* __restrict__ pm_out, int* __restrict__ hidx, float* __restrict__ amp) {
  __shared__ float r0[64], r1[64];
  __shared__ float s_pm;
  int t = threadIdx.x;
  if (t < 64) { r0[t] = pm_part[2*t]; r1[t] = pm_part[2*t+1]; }
  __syncthreads();
  if (t == 0) {
    float h1[32], h2v[16];
    for (int i=0;i<32;i++){ float z = b1[i]; h1[i] = z > 0.f ? z : 0.f; }
    for (int o=0;o<16;o++){ float acc = b2[o];
      for (int i=0;i<32;i++) acc += h1[i]*W2[i*16+o];
      h2v[o] = acc > 0.f ? acc : 0.f; }
    float md = b3[1];
    for (int i=0;i<16;i++) md += h2v[i]*W3[i*8+1];
    float S0 = 0.f, S1 = 0.f;
    for (int i=0;i<64;i++){ S0 += r0[i]; S1 += r1[i]; }
    s_pm = (S0 + md*S1) / (65537.0f * 4.0f);
    pm_out[0] = s_pm;
  }
  __syncthreads();
  if (t < 40) {
    const double SPECF[8] = {7.83, 528.0, 396.0, 2.5, 14.1, 432.0, 6.0, 30.0};
    int j = t / 5, mi = t % 5;
    double mult = (double)(mi + 1);
    double hf = SPECF[j] * mult;
    double ratio = hf * (131072.0 / 22050.0);
    hidx[t] = (int)floor(ratio + 0.5);
    amp[t] = (float)((double)fw[j] * pow(mult, -1.2) * (1.0 + (double)s_pm));
  }
}

// ---------------- gain curve, TRANSPOSED: gainT[c*256 + m] = gain[c+256m] --
__global__ __launch_bounds__(256) void k_gain(float* __restrict__ gainT,
    const float* __restrict__ bw, const int* __restrict__ hidx,
    const float* __restrict__ amp) {
  int j = blockIdx.x*256 + threadIdx.x;
  if (j > 65536) return;
  int i = (j == 65536) ? 65536 : (((j >> 8) & 255) | ((j & 255) << 8));
  float f = (float)((double)i * (22050.0/131072.0));
  float g = 1.0f;
  constexpr double LO[6] = {1,4,8,13,30,100};
  constexpr double HI[6] = {4,8,13,30,100,200};
  #pragma unroll
  for (int k = 0; k < 6; ++k) {
    float center = (float)(0.5*(LO[k]+HI[k]));
    float sig    = (float)(0.25*(HI[k]-LO[k]));
    float dm = (f - center)/sig;
    float mask = expf(-0.5f*dm*dm);
    if (f < (float)LO[k] || f > (float)HI[k]) mask = 0.f;
    float ang = (float)(6.283185307179586*0.5*(LO[k]+HI[k])) * (float)i / 22050.0f;
    g *= 1.0f + mask * bw[k] * (1.0f + 0.2f*sinf(ang));
  }
  for (int l = 0; l < 40; ++l) {
    int d = i - hidx[l];
    if (d >= -15 && d <= 15) {
      float dd = (float)d * 0.2f;
      g *= 1.0f + amp[l] * expf(-0.5f*dd*dd);
    }
  }
  gainT[j] = g;
}

// ---------------- forward pass 1: pack + column FFT + 4-step twiddle ------
__global__ __launch_bounds__(256, 4) void k_fwd1(const float* __restrict__ x,
                                                 h2* __restrict__ A, int s0) {
  __shared__ float smem[4096];       // 16 KB
  c32* sc = (c32*)smem;
  h2*  stg = (h2*)smem;
  int b = blockIdx.x; int sl = b >> 4; int g = b & 15;
  int t = threadIdx.x & 15, r = threadIdx.x >> 4;
  int n1 = g*16 + t;
  const float* xb = x + (size_t)(s0 + sl) * L_SIG;
  c32 v[16];
  #pragma unroll
  for (int j = 0; j < 16; ++j) {
    int n = n1 + 256*r + 4096*j;
    c32 z = mkc(0.f, 0.f);
    if (n < 32768)       { z.x = xb[2*n]; z.y = xb[2*n+1]; }
    else if (n == 32768) { z.x = xb[65536]; }
    v[j] = z;
  }
  fft256_team<-1>(v, r, t, sc);
  float a0 = -(2.0f*PI_F/65536.0f) * (float)(n1 * r);
  float a1 = -(2.0f*PI_F/4096.0f)  * (float)n1;
  c32 wb, wst;
  __sincosf(a0, &wb.y, &wb.x);
  __sincosf(a1, &wst.y, &wst.x);
  #pragma unroll
  for (int j = 0; j < 16; ++j) { v[j] = cmul(v[j], wb); wb = cmul(wb, wst); }
  __syncthreads();
  #pragma unroll
  for (int j = 0; j < 16; ++j)
    stg[(r + 16*j)*16 + t] = c2h(v[j]);
  __syncthreads();
  h2* Ab = A + (size_t)sl * NH;
  int u = threadIdx.x & 15, k2b = threadIdx.x >> 4;
  #pragma unroll
  for (int m = 0; m < 16; ++m) {
    int k2 = k2b + 16*m;
    Ab[(size_t)k2*256 + g*16 + u] = stg[k2*16 + u];
  }
}

// ---------------- fused fwd2 + mid + inv1 ---------------------------------
// Block (sl, p): owns column strip [16p..16p+15] and its mirror strip, plus
// 1-col smoothing halo: 36 LDS rows (row s holds column colmap(s)).
__device__ __forceinline__ int colmap(int s, int p) {
  return ((s < 18) ? (16*p - 1 + s) : (240 - 16*p + (s - 18))) & 255;
}

struct UP { c32 Uk, UK; float mk, mK, cn, sn; };
__device__ __forceinline__ UP pairup(const h2* rows, int rowk, int rowb, int k,
                                     const float* __restrict__ gT) {
  UP u;
  int kk = k & (NH-1);
  int Km = (NH - k) & (NH-1);
  c32 zk = h2c(rows[rowk*260 + (kk >> 8)]);
  c32 zb = h2c(rows[rowb*260 + (Km >> 8)]);
  c32 Aa = mkc(0.5f*(zk.x + zb.x), 0.5f*(zk.y - zb.y));
  c32 Bm = mkc(0.5f*(zk.x - zb.x), 0.5f*(zk.y + zb.y));
  __sincosf((PI_F/65536.0f)*(float)k, &u.sn, &u.cn);
  c32 wB = cmul(mkc(-u.sn, -u.cn), Bm);
  float gk = gT[((kk & 255) << 8) | (kk >> 8)];
  int K2 = NH - k;
  float gK = (K2 >= NH) ? gT[NH] : gT[((K2 & 255) << 8) | (K2 >> 8)];
  c32 Xk = mkc((Aa.x + wB.x)*gk,  (Aa.y + wB.y)*gk);
  c32 XK = mkc((Aa.x - wB.x)*gK, -(Aa.y - wB.y)*gK);
  float nk = Xk.x*Xk.x + Xk.y*Xk.y;
  float nK = XK.x*XK.x + XK.y*XK.y;
  float rk = rsqrtf(nk), rK = rsqrtf(nK);
  bool kv = (k >= 0);
  u.Uk = (nk > 0.f) ? mkc(Xk.x*rk, Xk.y*rk) : mkc(1.f, 0.f);
  u.UK = (nK > 0.f) ? mkc(XK.x*rK, XK.y*rK) : mkc(1.f, 0.f);
  u.mk = (kv && nk > 0.f) ? nk*rk : 0.f;
  u.mK = (kv && nK > 0.f) ? nK*rK : 0.f;
  return u;
}

__global__ __launch_bounds__(256, 3) void k_fmi(const h2* __restrict__ A,
                                                h2* __restrict__ B,
                                                const float* __restrict__ gT) {
  __shared__ float smem[13456];          // 36*260 h2 rows (37.4 KB) + 16 KB sc
  h2*  rows = (h2*)smem;
  c32* sc   = (c32*)(smem + 9360);
  int b = blockIdx.x; int sl = b >> 3; int p = b & 7;
  int tid = threadIdx.x; int t = tid & 15; int r = tid >> 4;
  const h2* Ab = A + (size_t)sl * NH;
  // ---- stage-in: 36 rows x 256 h2 = 36 x 64 float4 (float4 == 4 h2!) ----
  #pragma unroll
  for (int w = 0; w < 9; ++w) {
    int flat = tid + 256*w;              // 2304 = 36*64, exact
    int s = flat >> 6, i = flat & 63;
    int c = colmap(s, p);
    float4 z = ((const float4*)(Ab + (size_t)c*256))[i];
    *((float4*)(rows + s*260 + 4*i)) = z;
  }
  __syncthreads();
  // ---- forward row FFTs: 3 batches of 16 teams (in-place) ----
  for (int bt = 0; bt < 3; ++bt) {
    int slot = bt*16 + t;
    int se = (slot < 36) ? slot : slot - 36;   // dup teams: compute, don't write
    h2* rp = rows + se*260;
    c32 v[16];
    #pragma unroll
    for (int j = 0; j < 16; ++j) v[j] = h2c(rp[r + 16*j]);
    fft256_team<-1>(v, r, t, sc);
    if (slot < 36) {
      #pragma unroll
      for (int j = 0; j < 16; ++j) rp[r + 16*j] = c2h(v[j]);
    }
  }
  __syncthreads();
  // ---- mid: per-thread sliding-window walk over 18 consecutive bins ----
  int m = tid;
  int K0 = 16*p - 1 + 256*m;
  h2 o1[16], o2[16]; h2 o128 = __floats2half2_rn(0.f, 0.f);
  float m1a=0.f, m1b=0.f, m2a=0.f, m2b=0.f, cnp=0.f, snp=0.f;
  c32 u1p = mkc(1.f,0.f), u2p = mkc(1.f,0.f);
  const float invN = 1.0f/65536.0f;
  #pragma unroll
  for (int s = 0; s <= 17; ++s) {
    UP u = pairup(rows, s, 35 - s, K0 + s, gT);
    if (s >= 2) {
      int kq = K0 + s - 1;
      float msm = (kq == 0) ? m1b : 0.7f*m1b + 0.15f*(m1a + u.mk);
      float msh = (kq == 0) ? m2b : 0.7f*m2b + 0.15f*(m2a + u.mK);
      c32 XcL = mkc(u1p.x*msm, u1p.y*msm);
      c32 XcH = mkc(u2p.x*msh, u2p.y*msh);
      c32 E = mkc(0.5f*(XcL.x + XcH.x), 0.5f*(XcL.y - XcH.y));
      c32 D = mkc(0.5f*(XcL.x - XcH.x), 0.5f*(XcL.y + XcH.y));
      c32 O = cmul(mkc(cnp, snp), D);
      o1[s-2] = c2h(mkc((E.x - O.y)*invN, (E.y + O.x)*invN));
      o2[s-2] = c2h(mkc((E.x + O.y)*invN, (O.x - E.y)*invN));
    }
    m1a = m1b; m1b = u.mk; m2a = m2b; m2b = u.mK;
    u1p = u.Uk; u2p = u.UK; cnp = u.cn; snp = u.sn;
  }
  if (p == 7) {                    // self-mirror column 128 (bins 128+256m)
    int kb = 128 + 256*m;
    UP uA = pairup(rows, 16, 19, kb - 1, gT);
    UP u8 = pairup(rows, 17, 18, kb,     gT);
    UP uB = pairup(rows, 19, 16, kb + 1, gT);
    float msm = 0.7f*u8.mk + 0.15f*(uA.mk + uB.mk);
    float msh = 0.7f*u8.mK + 0.15f*(uA.mK + uB.mK);
    c32 XcL = mkc(u8.Uk.x*msm, u8.Uk.y*msm);
    c32 XcH = mkc(u8.UK.x*msh, u8.UK.y*msh);
    c32 E = mkc(0.5f*(XcL.x + XcH.x), 0.5f*(XcL.y - XcH.y));
    c32 D = mkc(0.5f*(XcL.x - XcH.x), 0.5f*(XcL.y + XcH.y));
    c32 O = cmul(mkc(u8.cn, u8.sn), D);
    o128 = c2h(mkc((E.x - O.y)*invN, (E.y + O.x)*invN));
  }
  __syncthreads();                 // all reads done -> overwrite Z with Zc
  #pragma unroll
  for (int s = 1; s <= 16; ++s) {
    rows[s*260 + m] = o1[s-1];
    int kq = K0 + s;
    if (kq != 0) {
      int Kq = (NH - kq) & (NH-1);
      rows[(35 - s)*260 + (Kq >> 8)] = o2[s-1];
    }
  }
  if (p == 7) rows[17*260 + m] = o128;
  __syncthreads();
  // ---- inverse column FFTs + twiddle + store B ----
  h2* Bb = B + (size_t)sl * NH;
  int nb = (p == 7) ? 3 : 2;
  for (int bt = 0; bt < nb; ++bt) {
    int row, cb;
    if (bt == 0)      { row = 1 + t;  cb = 16*p; }
    else if (bt == 1) { row = 19 + t; cb = 241 - 16*p; }
    else              { row = (t == 0) ? 17 : (1 + t); cb = 128; }
    h2* rp = rows + row*260;
    c32 v[16];
    #pragma unroll
    for (int j = 0; j < 16; ++j) v[j] = h2c(rp[r + 16*j]);
    fft256_team<1>(v, r, t, sc);
    int a = (bt == 2) ? 128 : ((cb + t) & 255);
    float a0 = (2.0f*PI_F/65536.0f) * (float)(a * r);
    float a1 = (2.0f*PI_F/4096.0f)  * (float)a;
    c32 wb, wst;
    __sincosf(a0, &wb.y, &wb.x);
    __sincosf(a1, &wst.y, &wst.x);
    #pragma unroll
    for (int j = 0; j < 16; ++j) { v[j] = cmul(v[j], wb); wb = cmul(wb, wst); }
    __syncthreads();
    h2* stg = (h2*)sc;
    #pragma unroll
    for (int j = 0; j < 16; ++j) stg[(r + 16*j)*16 + t] = c2h(v[j]);
    __syncthreads();
    int u = tid & 15, m2b_ = tid >> 4;
    if (bt < 2) {
      int cv = cb + u;
      #pragma unroll
      for (int q = 0; q < 16; ++q) {
        int m2 = m2b_ + 16*q;
        if (cv < 256) Bb[(size_t)m2*256 + cv] = stg[m2*16 + u];
      }
    } else if (u == 0) {
      #pragma unroll
      for (int q = 0; q < 16; ++q) {
        int m2 = m2b_ + 16*q;
        Bb[(size_t)m2*256 + 128] = stg[m2*16 + 0];
      }
    }
  }
}

// ---------------- inverse pass 2: row FFT (+) -> real output --------------
__global__ __launch_bounds__(256, 4) void k_inv2(const h2* __restrict__ B,
                                                 float* __restrict__ out, int s0) {
  __shared__ float smem[4160];
  c32* sc = (c32*)smem;
  h2* stg = (h2*)smem;
  int b = blockIdx.x; int sl = b >> 4; int g = b & 15;
  int tid = threadIdx.x;
  int t = tid & 15, r = tid >> 4;
  const h2* Bb = B + (size_t)sl * NH;
  #pragma unroll
  for (int m = 0; m < 4; ++m) {
    int flat = tid + 256*m;
    int row = flat >> 6, i = flat & 63;
    float4 z = ((const float4*)(Bb + (size_t)(g*16 + row)*256))[i];
    *((float4*)&stg[row*260 + 4*i]) = z;
  }
  __syncthreads();
  c32 v[16];
  #pragma unroll
  for (int j = 0; j < 16; ++j)
    v[j] = h2c(stg[t*260 + r + 16*j]);
  fft256_team<1>(v, r, t, sc);
  float* yb = out + (size_t)(s0 + sl) * L_SIG;
  int m2 = g*16 + t;
  #pragma unroll
  for (int j = 0; j < 16; ++j) {
    int m1 = r + 16*j;
    if (m1 <= 127) {
      int m = m2 + 256*m1;
      yb[2*m]   = v[j].x;
      yb[2*m+1] = v[j].y;
    } else if (m1 == 128 && m2 == 0) {
      yb[65536] = v[j].x;
    }
  }
}

// --------------------------------------------------------------------------
extern "C" void kernel_launch(void* const* d_in, const int* in_sizes, int n_in,
                              void* d_out, int out_size, void* d_ws, size_t ws_size,
                              hipStream_t stream) {
  const float* x  = (const float*)d_in[0];
  const float* bw = (const float*)d_in[1];
  const float* fw = (const float*)d_in[2];
  const float* hp = (const float*)d_in[3];
  // d_in[4] = W1: mathematically unused (tn==0 at the only sampled row)
  const float* b1 = (const float*)d_in[5];
  const float* W2 = (const float*)d_in[6];
  const float* b2 = (const float*)d_in[7];
  const float* W3 = (const float*)d_in[8];
  const float* b3 = (const float*)d_in[9];
  float* out = (float*)d_out;
  char* ws = (char*)d_ws;

  const size_t perSig = (size_t)NH * sizeof(h2);              // 256 KiB / signal / buffer
  const size_t tail   = (size_t)L_SIG * sizeof(float) + 2048; // gainT + scalars + pm_part
  size_t cap = (ws_size > tail) ? (ws_size - tail) / (2*perSig) : 1;
  int chunk = (cap >= (size_t)NSIG) ? NSIG : (cap < 1 ? 1 : (int)cap);

  h2*    A     = (h2*)ws;
  h2*    Bb    = (h2*)(ws + (size_t)chunk*perSig);
  float* gainT = (float*)(ws + 2*(size_t)chunk*perSig);
  float* pm    = gainT + L_SIG;
  int*   hidx  = (int*)(pm + 1);
  float* amp   = (float*)(hidx + 40);
  float* pm_part = amp + 40;          // 128 floats

  k_pm   <<<64, 256, 0, stream>>>(hp, pm_part);
  k_prep2<<<1,  256, 0, stream>>>(b1, W2, b2, W3, b3, fw, pm_part, pm, hidx, amp);
  k_gain <<<257,256, 0, stream>>>(gainT, bw, hidx, amp);

  for (int s0 = 0; s0 < NSIG; s0 += chunk) {
    int S = (NSIG - s0 < chunk) ? (NSIG - s0) : chunk;
    k_fwd1<<<S*16, 256, 0, stream>>>(x, A, s0);
    k_fmi <<<S*8,  256, 0, stream>>>(A, Bb, gainT);
    k_inv2<<<S*16, 256, 0, stream>>>(Bb, out, s0);
  }
}

// Round 7
// 325.283 us; speedup vs baseline: 1.1297x; 1.1297x over previous
//
#include <hip/hip_runtime.h>
#include <hip/hip_fp16.h>
#include <math.h>

#define L_SIG 65537
#define NH    65536     // half-size complex FFT length (NFFT/2)
#define NSIG  256
#define PI_F  3.14159265358979323846f

struct alignas(8) c32 { float x, y; };   // 8B-aligned -> LDS ds_*_b64
typedef __half2 h2;                      // h2 = 4 BYTES; float4 = 4 h2
__device__ __forceinline__ c32 mkc(float a, float b){ c32 r; r.x=a; r.y=b; return r; }
__device__ __forceinline__ c32 cadd(c32 a, c32 b){ return mkc(a.x+b.x, a.y+b.y); }
__device__ __forceinline__ c32 csub(c32 a, c32 b){ return mkc(a.x-b.x, a.y-b.y); }
__device__ __forceinline__ c32 cmul(c32 a, c32 b){ return mkc(a.x*b.x - a.y*b.y, a.x*b.y + a.y*b.x); }
__device__ __forceinline__ h2  c2h(c32 a){ return __floats2half2_rn(a.x, a.y); }
__device__ __forceinline__ c32 h2c(h2 a){ float2 f = __half22float2(a); return mkc(f.x, f.y); }

// ---------------- 16-point FFT in registers (radix-4 x 2) ------------------
template<int S>
__device__ __forceinline__ void fft16(c32 v[16]) {
  constexpr float C16[16] = {
    1.0f, 0.9238795325112867f, 0.7071067811865476f, 0.3826834323650898f,
    0.0f,-0.3826834323650898f,-0.7071067811865476f,-0.9238795325112867f,
   -1.0f,-0.9238795325112867f,-0.7071067811865476f,-0.3826834323650898f,
    0.0f, 0.3826834323650898f, 0.7071067811865476f, 0.9238795325112867f };
  constexpr float S16[16] = {
    0.0f, 0.3826834323650898f, 0.7071067811865476f, 0.9238795325112867f,
    1.0f, 0.9238795325112867f, 0.7071067811865476f, 0.3826834323650898f,
    0.0f,-0.3826834323650898f,-0.7071067811865476f,-0.9238795325112867f,
   -1.0f,-0.9238795325112867f,-0.7071067811865476f,-0.3826834323650898f };
  c32 s[16];
  #pragma unroll
  for (int b0 = 0; b0 < 4; ++b0) {
    c32 x0=v[b0], x1=v[b0+4], x2=v[b0+8], x3=v[b0+12];
    c32 u0=cadd(x0,x2), u1=csub(x0,x2), u2=cadd(x1,x3), u3=csub(x1,x3);
    c32 iu3 = mkc(-u3.y, u3.x);
    c32 yy[4];
    yy[0]=cadd(u0,u2); yy[2]=csub(u0,u2);
    if (S < 0) { yy[1]=csub(u1,iu3); yy[3]=cadd(u1,iu3); }
    else       { yy[1]=cadd(u1,iu3); yy[3]=csub(u1,iu3); }
    #pragma unroll
    for (int c0 = 0; c0 < 4; ++c0) {
      const int p = (b0*c0) & 15;
      c32 w = mkc(C16[p], (S<0) ? -S16[p] : S16[p]);
      s[c0*4 + b0] = cmul(yy[c0], w);
    }
  }
  #pragma unroll
  for (int c0 = 0; c0 < 4; ++c0) {
    c32 x0=s[c0*4+0], x1=s[c0*4+1], x2=s[c0*4+2], x3=s[c0*4+3];
    c32 u0=cadd(x0,x2), u1=csub(x0,x2), u2=cadd(x1,x3), u3=csub(x1,x3);
    c32 iu3 = mkc(-u3.y, u3.x);
    c32 yy[4];
    yy[0]=cadd(u0,u2); yy[2]=csub(u0,u2);
    if (S < 0) { yy[1]=csub(u1,iu3); yy[3]=cadd(u1,iu3); }
    else       { yy[1]=cadd(u1,iu3); yy[3]=csub(u1,iu3); }
    v[c0+0]=yy[0]; v[c0+4]=yy[1]; v[c0+8]=yy[2]; v[c0+12]=yy[3];
  }
}

// ------------- 256-pt FFT, 16-thread team, 16 KB two-phase transpose ------
template<int S>
__device__ __forceinline__ void fft256_team(c32 v[16], int r, int t, c32* sc) {
  fft16<S>(v);
  float ang = (float)S * (2.0f*PI_F/256.0f) * (float)r;
  c32 st; __sincosf(ang, &st.y, &st.x);
  c32 w = st;
  #pragma unroll
  for (int c = 1; c < 16; ++c) { v[c] = cmul(v[c], w); w = cmul(w, st); }
  int p  = r*8 + (t & 7);
  int fr = (r & 1) << 3;
  __syncthreads();
  if (t < 8) {
    #pragma unroll
    for (int c = 0; c < 16; ++c)
      sc[c*128 + (p ^ ((c & 1) << 3))] = v[c];
  }
  __syncthreads();
  if (t < 8) {
    #pragma unroll
    for (int a = 0; a < 16; ++a)
      v[a] = sc[r*128 + ((a*8 + (t & 7)) ^ fr)];
  }
  __syncthreads();
  if (t >= 8) {
    #pragma unroll
    for (int c = 0; c < 16; ++c)
      sc[c*128 + (p ^ ((c & 1) << 3))] = v[c];
  }
  __syncthreads();
  if (t >= 8) {
    #pragma unroll
    for (int a = 0; a < 16; ++a)
      v[a] = sc[r*128 + ((a*8 + (t & 7)) ^ fr)];
  }
  fft16<S>(v);
}

// ---------------- prep A: pm partial sums (md-separable) -------------------
__global__ __launch_bounds__(256) void k_pm(const float* __restrict__ hp,
                                            float* __restrict__ pm_part) {
  __shared__ float r0[256], r1[256];
  int t = threadIdx.x, b = blockIdx.x;
  int gid = b*256 + t;
  float s0 = 0.f, s1 = 0.f;
  for (int tt = gid; tt < 65537; tt += 16384) {
    int ci = (tt * 8) / 65537;
    float cs = hp[ci*4+0] + hp[ci*4+1] + hp[ci*4+2] + hp[ci*4+3];
    float ang = (6.2831853071795864769f * (float)tt) / 65537.0f;
    s0 += cs;
    s1 += cs * sinf(ang);
  }
  r0[t] = s0; r1[t] = s1;
  __syncthreads();
  for (int s = 128; s > 0; s >>= 1) {
    if (t < s) { r0[t] += r0[t+s]; r1[t] += r1[t+s]; }
    __syncthreads();
  }
  if (t == 0) { pm_part[2*b] = r0[0]; pm_part[2*b+1] = r1[0]; }
}

// ---------------- prep B: MLP md, final pm, spectral line table ------------
__global__ __launch_bounds__(256) void k_prep2(const float* __restrict__ b1,
    const float* __restrict__ W2, const float* __restrict__ b2,
    const float* __restrict__ W3, const float* __restrict__ b3,
    const float* __restrict__ fw, const float* __restrict__ pm_part,
    float* __restrict__ pm_out, int* __restrict__ hidx, float* __restrict__ amp) {
  __shared__ float r0[64], r1[64];
  __shared__ float s_pm;
  int t = threadIdx.x;
  if (t < 64) { r0[t] = pm_part[2*t]; r1[t] = pm_part[2*t+1]; }
  __syncthreads();
  if (t == 0) {
    float h1[32], h2v[16];
    for (int i=0;i<32;i++){ float z = b1[i]; h1[i] = z > 0.f ? z : 0.f; }
    for (int o=0;o<16;o++){ float acc = b2[o];
      for (int i=0;i<32;i++) acc += h1[i]*W2[i*16+o];
      h2v[o] = acc > 0.f ? acc : 0.f; }
    float md = b3[1];
    for (int i=0;i<16;i++) md += h2v[i]*W3[i*8+1];
    float S0 = 0.f, S1 = 0.f;
    for (int i=0;i<64;i++){ S0 += r0[i]; S1 += r1[i]; }
    s_pm = (S0 + md*S1) / (65537.0f * 4.0f);
    pm_out[0] = s_pm;
  }
  __syncthreads();
  if (t < 40) {
    const double SPECF[8] = {7.83, 528.0, 396.0, 2.5, 14.1, 432.0, 6.0, 30.0};
    int j = t / 5, mi = t % 5;
    double mult = (double)(mi + 1);
    double hf = SPECF[j] * mult;
    double ratio = hf * (131072.0 / 22050.0);
    hidx[t] = (int)floor(ratio + 0.5);
    amp[t] = (float)((double)fw[j] * pow(mult, -1.2) * (1.0 + (double)s_pm));
  }
}

// ---------------- gain curve, TRANSPOSED: gainT[c*256 + m] = gain[c+256m] --
__global__ __launch_bounds__(256) void k_gain(float* __restrict__ gainT,
    const float* __restrict__ bw, const int* __restrict__ hidx,
    const float* __restrict__ amp) {
  int j = blockIdx.x*256 + threadIdx.x;
  if (j > 65536) return;
  int i = (j == 65536) ? 65536 : (((j >> 8) & 255) | ((j & 255) << 8));
  float f = (float)((double)i * (22050.0/131072.0));
  float g = 1.0f;
  constexpr double LO[6] = {1,4,8,13,30,100};
  constexpr double HI[6] = {4,8,13,30,100,200};
  #pragma unroll
  for (int k = 0; k < 6; ++k) {
    float center = (float)(0.5*(LO[k]+HI[k]));
    float sig    = (float)(0.25*(HI[k]-LO[k]));
    float dm = (f - center)/sig;
    float mask = expf(-0.5f*dm*dm);
    if (f < (float)LO[k] || f > (float)HI[k]) mask = 0.f;
    float ang = (float)(6.283185307179586*0.5*(LO[k]+HI[k])) * (float)i / 22050.0f;
    g *= 1.0f + mask * bw[k] * (1.0f + 0.2f*sinf(ang));
  }
  for (int l = 0; l < 40; ++l) {
    int d = i - hidx[l];
    if (d >= -15 && d <= 15) {
      float dd = (float)d * 0.2f;
      g *= 1.0f + amp[l] * expf(-0.5f*dd*dd);
    }
  }
  gainT[j] = g;
}

// ---------------- forward pass 1: pack + column FFT + 4-step twiddle ------
__global__ __launch_bounds__(256, 4) void k_fwd1(const float* __restrict__ x,
                                                 h2* __restrict__ A, int s0) {
  __shared__ float smem[4096];       // 16 KB
  c32* sc = (c32*)smem;
  h2*  stg = (h2*)smem;
  int b = blockIdx.x; int sl = b >> 4; int g = b & 15;
  int t = threadIdx.x & 15, r = threadIdx.x >> 4;
  int n1 = g*16 + t;
  const float* xb = x + (size_t)(s0 + sl) * L_SIG;
  c32 v[16];
  #pragma unroll
  for (int j = 0; j < 16; ++j) {
    int n = n1 + 256*r + 4096*j;
    c32 z = mkc(0.f, 0.f);
    if (n < 32768)       { z.x = xb[2*n]; z.y = xb[2*n+1]; }
    else if (n == 32768) { z.x = xb[65536]; }
    v[j] = z;
  }
  fft256_team<-1>(v, r, t, sc);
  float a0 = -(2.0f*PI_F/65536.0f) * (float)(n1 * r);
  float a1 = -(2.0f*PI_F/4096.0f)  * (float)n1;
  c32 wb, wst;
  __sincosf(a0, &wb.y, &wb.x);
  __sincosf(a1, &wst.y, &wst.x);
  #pragma unroll
  for (int j = 0; j < 16; ++j) { v[j] = cmul(v[j], wb); wb = cmul(wb, wst); }
  __syncthreads();
  #pragma unroll
  for (int j = 0; j < 16; ++j)
    stg[(r + 16*j)*16 + t] = c2h(v[j]);
  __syncthreads();
  h2* Ab = A + (size_t)sl * NH;
  int u = threadIdx.x & 15, k2b = threadIdx.x >> 4;
  #pragma unroll
  for (int m = 0; m < 16; ++m) {
    int k2 = k2b + 16*m;
    Ab[(size_t)k2*256 + g*16 + u] = stg[k2*16 + u];
  }
}

// ---------------- forward pass 2: row FFT -> ZT[k2*256 + k1] (coalesced) --
__global__ __launch_bounds__(256, 4) void k_fwd2(const h2* __restrict__ A,
                                                 h2* __restrict__ ZT) {
  __shared__ float smem[4160];       // 16.6 KB: stg-in / sc / stg-out (aliased)
  c32* sc = (c32*)smem;
  h2* stg = (h2*)smem;
  int b = blockIdx.x; int sl = b >> 4; int g = b & 15;
  int tid = threadIdx.x;
  int t = tid & 15, r = tid >> 4;
  const h2* Ab = A + (size_t)sl * NH;
  #pragma unroll
  for (int m = 0; m < 4; ++m) {
    int flat = tid + 256*m;
    int row = flat >> 6, i = flat & 63;
    float4 z = ((const float4*)(Ab + (size_t)(g*16 + row)*256))[i];
    *((float4*)&stg[row*260 + 4*i]) = z;
  }
  __syncthreads();
  c32 v[16];
  #pragma unroll
  for (int j = 0; j < 16; ++j)
    v[j] = h2c(stg[t*260 + r + 16*j]);     // row k2=g16+t, FFT over n1 -> k1
  fft256_team<-1>(v, r, t, sc);
  __syncthreads();                         // drain fft sc reads
  #pragma unroll
  for (int j = 0; j < 16; ++j)
    stg[t*260 + r + 16*j] = c2h(v[j]);     // [k2local][k1], 2-way banks
  __syncthreads();
  h2* Zb = ZT + (size_t)sl * NH;
  #pragma unroll
  for (int w = 0; w < 4; ++w) {
    int flat = tid + 256*w;
    int k2l = flat >> 6, i = flat & 63;
    *((float4*)(Zb + (size_t)(g*16 + k2l)*256 + 4*i)) =
        *((const float4*)(stg + k2l*260 + 4*i));
  }
}

// ---------------- fused mid + inv1, strip = 8 columns ----------------------
// ZT layout: ZT[(k&255)*256 + (k>>8)] — mid's bin walk reads coalesced rows.
// Block (sl,p): owns k2 rows [8p..8p+7] + mirrors [(249-8p)..(256-8p)],
// sliding-window mid (verbatim round-6 verified math) -> 16 LDS row slots
// (+slot16 for k2=128 at p==15; it lives ABOVE the 16KB sc alias so it
// survives batch 0) -> inverse column FFT -> B[m2*256 + k2].
struct UP { c32 Uk, UK; float mk, mK, cn, sn; };
__device__ __forceinline__ UP pairupG(const h2* __restrict__ Zs, int k,
                                      const float* __restrict__ gT) {
  UP u;
  int kk = k & (NH-1);
  int Km = (NH - k) & (NH-1);
  int ik = ((kk & 255) << 8) | (kk >> 8);
  int ib = ((Km & 255) << 8) | (Km >> 8);
  c32 zk = h2c(Zs[ik]);
  c32 zb = h2c(Zs[ib]);
  c32 Aa = mkc(0.5f*(zk.x + zb.x), 0.5f*(zk.y - zb.y));
  c32 Bm = mkc(0.5f*(zk.x - zb.x), 0.5f*(zk.y + zb.y));
  __sincosf((PI_F/65536.0f)*(float)k, &u.sn, &u.cn);
  c32 wB = cmul(mkc(-u.sn, -u.cn), Bm);
  float gk = gT[ik];
  int K2 = NH - k;
  float gK = (K2 >= NH) ? gT[NH] : gT[ib];
  c32 Xk = mkc((Aa.x + wB.x)*gk,  (Aa.y + wB.y)*gk);
  c32 XK = mkc((Aa.x - wB.x)*gK, -(Aa.y - wB.y)*gK);
  float nk = Xk.x*Xk.x + Xk.y*Xk.y;
  float nK = XK.x*XK.x + XK.y*XK.y;
  float rk = rsqrtf(nk), rK = rsqrtf(nK);
  bool kv = (k >= 0);
  u.Uk = (nk > 0.f) ? mkc(Xk.x*rk, Xk.y*rk) : mkc(1.f, 0.f);
  u.UK = (nK > 0.f) ? mkc(XK.x*rK, XK.y*rK) : mkc(1.f, 0.f);
  u.mk = (kv && nk > 0.f) ? nk*rk : 0.f;
  u.mK = (kv && nK > 0.f) ? nK*rK : 0.f;
  return u;
}

__global__ __launch_bounds__(256, 4) void k_mi(const h2* __restrict__ ZT,
                                               h2* __restrict__ B,
                                               const float* __restrict__ gT) {
  __shared__ float smem[4420];          // 17 x 260 h2 = 17.3 KB; first 16 KB = sc/stg
  h2*  rowsO = (h2*)smem;
  c32* sc    = (c32*)smem;
  h2*  stg   = (h2*)smem;
  int b = blockIdx.x; int sl = b >> 4; int p = b & 15;
  int tid = threadIdx.x; int t = tid & 15; int r = tid >> 4;
  const h2* Zs = ZT + (size_t)sl * NH;
  h2* Bb = B + (size_t)sl * NH;
  int m = tid;
  int K0 = 8*p - 1 + 256*m;
  // ---- mid: sliding-window walk (outputs bins K0+1 .. K0+8 and mirrors) --
  h2 o1[8], o2[8]; h2 o128 = __floats2half2_rn(0.f, 0.f);
  float m1a=0.f, m1b=0.f, m2a=0.f, m2b=0.f, cnp=0.f, snp=0.f;
  c32 u1p = mkc(1.f,0.f), u2p = mkc(1.f,0.f);
  const float invN = 1.0f/65536.0f;
  #pragma unroll
  for (int s = 0; s <= 9; ++s) {
    UP u = pairupG(Zs, K0 + s, gT);
    if (s >= 2) {
      int kq = K0 + s - 1;
      float msm = (kq == 0) ? m1b : 0.7f*m1b + 0.15f*(m1a + u.mk);
      float msh = (kq == 0) ? m2b : 0.7f*m2b + 0.15f*(m2a + u.mK);
      c32 XcL = mkc(u1p.x*msm, u1p.y*msm);
      c32 XcH = mkc(u2p.x*msh, u2p.y*msh);
      c32 E = mkc(0.5f*(XcL.x + XcH.x), 0.5f*(XcL.y - XcH.y));
      c32 D = mkc(0.5f*(XcL.x - XcH.x), 0.5f*(XcL.y + XcH.y));
      c32 O = cmul(mkc(cnp, snp), D);
      o1[s-2] = c2h(mkc((E.x - O.y)*invN, (E.y + O.x)*invN));
      o2[s-2] = c2h(mkc((E.x + O.y)*invN, (O.x - E.y)*invN));
    }
    m1a = m1b; m1b = u.mk; m2a = m2b; m2b = u.mK;
    u1p = u.Uk; u2p = u.UK; cnp = u.cn; snp = u.sn;
  }
  if (p == 15) {                    // self-mirror column k2 = 128
    int kb = 128 + 256*m;
    UP uA = pairupG(Zs, kb - 1, gT);
    UP u8 = pairupG(Zs, kb,     gT);
    UP uB = pairupG(Zs, kb + 1, gT);
    float msm = 0.7f*u8.mk + 0.15f*(uA.mk + uB.mk);
    float msh = 0.7f*u8.mK + 0.15f*(uA.mK + uB.mK);
    c32 XcL = mkc(u8.Uk.x*msm, u8.Uk.y*msm);
    c32 XcH = mkc(u8.UK.x*msh, u8.UK.y*msh);
    c32 E = mkc(0.5f*(XcL.x + XcH.x), 0.5f*(XcL.y - XcH.y));
    c32 D = mkc(0.5f*(XcL.x - XcH.x), 0.5f*(XcL.y + XcH.y));
    c32 O = cmul(mkc(u8.cn, u8.sn), D);
    o128 = c2h(mkc((E.x - O.y)*invN, (E.y + O.x)*invN));
  }
  // ---- write row slots: slot s-1 = row 8p+s-1 (o1); slot 16-s = mirror ---
  #pragma unroll
  for (int s = 1; s <= 8; ++s) {
    rowsO[(s-1)*260 + m] = o1[s-1];
    int kq = K0 + s;
    if (kq != 0) {
      int Kq = (NH - kq) & (NH-1);
      rowsO[(16 - s)*260 + (Kq >> 8)] = o2[s-1];
    }
  }
  if (p == 15) rowsO[16*260 + m] = o128;
  __syncthreads();
  // ---- inverse FFT batch 0: 16 row slots -> B[m2*256 + k2] --------------
  {
    int aT = (t < 8) ? (8*p + t) : (249 - 8*p + (t - 8));  // team's k2 (256 = dup, masked)
    c32 v[16];
    #pragma unroll
    for (int j = 0; j < 16; ++j) v[j] = h2c(rowsO[t*260 + r + 16*j]);
    fft256_team<1>(v, r, t, sc);         // sc aliases slots 0..15 (already consumed)
    float a0 = (2.0f*PI_F/65536.0f) * (float)(aT * r);
    float a1 = (2.0f*PI_F/4096.0f)  * (float)aT;
    c32 wb, wst;
    __sincosf(a0, &wb.y, &wb.x);
    __sincosf(a1, &wst.y, &wst.x);
    #pragma unroll
    for (int j = 0; j < 16; ++j) { v[j] = cmul(v[j], wb); wb = cmul(wb, wst); }
    __syncthreads();
    #pragma unroll
    for (int j = 0; j < 16; ++j) stg[(r + 16*j)*16 + t] = c2h(v[j]);
    __syncthreads();
    int u = tid & 15, mb = tid >> 4;
    int aU = (u < 8) ? (8*p + u) : (249 - 8*p + (u - 8));
    if (aU < 256) {
      #pragma unroll
      for (int q = 0; q < 16; ++q) {
        int m2 = mb + 16*q;
        Bb[(size_t)m2*256 + aU] = stg[m2*16 + u];
      }
    }
  }
  if (p == 15) {                    // batch 1: row 128 (slot 16 above sc, intact)
    c32 v[16];
    #pragma unroll
    for (int j = 0; j < 16; ++j) v[j] = h2c(rowsO[16*260 + r + 16*j]);
    fft256_team<1>(v, r, t, sc);
    float a0 = (2.0f*PI_F/65536.0f) * (float)(128 * r);
    float a1 = (2.0f*PI_F/4096.0f)  * 128.0f;
    c32 wb, wst;
    __sincosf(a0, &wb.y, &wb.x);
    __sincosf(a1, &wst.y, &wst.x);
    #pragma unroll
    for (int j = 0; j < 16; ++j) { v[j] = cmul(v[j], wb); wb = cmul(wb, wst); }
    __syncthreads();
    #pragma unroll
    for (int j = 0; j < 16; ++j) stg[(r + 16*j)*16 + t] = c2h(v[j]);
    __syncthreads();
    int u = tid & 15, mb = tid >> 4;
    if (u == 0) {
      #pragma unroll
      for (int q = 0; q < 16; ++q) {
        int m2 = mb + 16*q;
        Bb[(size_t)m2*256 + 128] = stg[m2*16 + 0];
      }
    }
  }
}

// ---------------- inverse pass 2: row FFT (+) -> real output --------------
__global__ __launch_bounds__(256, 4) void k_inv2(const h2* __restrict__ B,
                                                 float* __restrict__ out, int s0) {
  __shared__ float smem[4160];
  c32* sc = (c32*)smem;
  h2* stg = (h2*)smem;
  int b = blockIdx.x; int sl = b >> 4; int g = b & 15;
  int tid = threadIdx.x;
  int t = tid & 15, r = tid >> 4;
  const h2* Bb = B + (size_t)sl * NH;
  #pragma unroll
  for (int m = 0; m < 4; ++m) {
    int flat = tid + 256*m;
    int row = flat >> 6, i = flat & 63;
    float4 z = ((const float4*)(Bb + (size_t)(g*16 + row)*256))[i];
    *((float4*)&stg[row*260 + 4*i]) = z;
  }
  __syncthreads();
  c32 v[16];
  #pragma unroll
  for (int j = 0; j < 16; ++j)
    v[j] = h2c(stg[t*260 + r + 16*j]);
  fft256_team<1>(v, r, t, sc);
  float* yb = out + (size_t)(s0 + sl) * L_SIG;
  int m2 = g*16 + t;
  #pragma unroll
  for (int j = 0; j < 16; ++j) {
    int m1 = r + 16*j;
    if (m1 <= 127) {
      int m = m2 + 256*m1;
      yb[2*m]   = v[j].x;
      yb[2*m+1] = v[j].y;
    } else if (m1 == 128 && m2 == 0) {
      yb[65536] = v[j].x;
    }
  }
}

// --------------------------------------------------------------------------
extern "C" void kernel_launch(void* const* d_in, const int* in_sizes, int n_in,
                              void* d_out, int out_size, void* d_ws, size_t ws_size,
                              hipStream_t stream) {
  const float* x  = (const float*)d_in[0];
  const float* bw = (const float*)d_in[1];
  const float* fw = (const float*)d_in[2];
  const float* hp = (const float*)d_in[3];
  // d_in[4] = W1: mathematically unused (tn==0 at the only sampled row)
  const float* b1 = (const float*)d_in[5];
  const float* W2 = (const float*)d_in[6];
  const float* b2 = (const float*)d_in[7];
  const float* W3 = (const float*)d_in[8];
  const float* b3 = (const float*)d_in[9];
  float* out = (float*)d_out;
  char* ws = (char*)d_ws;

  const size_t perSig = (size_t)NH * sizeof(h2);              // 256 KiB / signal / buffer
  const size_t tail   = (size_t)L_SIG * sizeof(float) + 2048; // gainT + scalars + pm_part
  size_t cap = (ws_size > tail) ? (ws_size - tail) / (2*perSig) : 1;
  int chunk = (cap >= (size_t)NSIG) ? NSIG : (cap < 1 ? 1 : (int)cap);

  h2*    A     = (h2*)ws;
  h2*    Bb    = (h2*)(ws + (size_t)chunk*perSig);
  float* gainT = (float*)(ws + 2*(size_t)chunk*perSig);
  float* pm    = gainT + L_SIG;
  int*   hidx  = (int*)(pm + 1);
  float* amp   = (float*)(hidx + 40);
  float* pm_part = amp + 40;          // 128 floats

  k_pm   <<<64, 256, 0, stream>>>(hp, pm_part);
  k_prep2<<<1,  256, 0, stream>>>(b1, W2, b2, W3, b3, fw, pm_part, pm, hidx, amp);
  k_gain <<<257,256, 0, stream>>>(gainT, bw, hidx, amp);

  for (int s0 = 0; s0 < NSIG; s0 += chunk) {
    int S = (NSIG - s0 < chunk) ? (NSIG - s0) : chunk;
    k_fwd1<<<S*16, 256, 0, stream>>>(x, A, s0);
    k_fwd2<<<S*16, 256, 0, stream>>>(A, Bb);      // -> ZT (transposed)
    k_mi  <<<S*16, 256, 0, stream>>>(Bb, A, gainT); // mid + inv1 -> B (m2-major)
    k_inv2<<<S*16, 256, 0, stream>>>(A, out, s0);
  }
}

// Round 8
// 290.709 us; speedup vs baseline: 1.2641x; 1.1189x over previous
//
#include <hip/hip_runtime.h>
#include <hip/hip_fp16.h>
#include <math.h>

#define L_SIG 65537
#define NH    65536     // half-size complex FFT length (NFFT/2)
#define NSIG  256
#define PI_F  3.14159265358979323846f

struct alignas(8) c32 { float x, y; };   // 8B-aligned -> LDS ds_*_b64
typedef __half2 h2;                      // h2 = 4 BYTES; float4 = 4 h2
__device__ __forceinline__ c32 mkc(float a, float b){ c32 r; r.x=a; r.y=b; return r; }
__device__ __forceinline__ c32 cadd(c32 a, c32 b){ return mkc(a.x+b.x, a.y+b.y); }
__device__ __forceinline__ c32 csub(c32 a, c32 b){ return mkc(a.x-b.x, a.y-b.y); }
__device__ __forceinline__ c32 cmul(c32 a, c32 b){ return mkc(a.x*b.x - a.y*b.y, a.x*b.y + a.y*b.x); }
__device__ __forceinline__ h2  c2h(c32 a){ return __floats2half2_rn(a.x, a.y); }
__device__ __forceinline__ c32 h2c(h2 a){ float2 f = __half22float2(a); return mkc(f.x, f.y); }

// ---------------- 16-point FFT in registers (radix-4 x 2) ------------------
template<int S>
__device__ __forceinline__ void fft16(c32 v[16]) {
  constexpr float C16[16] = {
    1.0f, 0.9238795325112867f, 0.7071067811865476f, 0.3826834323650898f,
    0.0f,-0.3826834323650898f,-0.7071067811865476f,-0.9238795325112867f,
   -1.0f,-0.9238795325112867f,-0.7071067811865476f,-0.3826834323650898f,
    0.0f, 0.3826834323650898f, 0.7071067811865476f, 0.9238795325112867f };
  constexpr float S16[16] = {
    0.0f, 0.3826834323650898f, 0.7071067811865476f, 0.9238795325112867f,
    1.0f, 0.9238795325112867f, 0.7071067811865476f, 0.3826834323650898f,
    0.0f,-0.3826834323650898f,-0.7071067811865476f,-0.9238795325112867f,
   -1.0f,-0.9238795325112867f,-0.7071067811865476f,-0.3826834323650898f };
  c32 s[16];
  #pragma unroll
  for (int b0 = 0; b0 < 4; ++b0) {
    c32 x0=v[b0], x1=v[b0+4], x2=v[b0+8], x3=v[b0+12];
    c32 u0=cadd(x0,x2), u1=csub(x0,x2), u2=cadd(x1,x3), u3=csub(x1,x3);
    c32 iu3 = mkc(-u3.y, u3.x);
    c32 yy[4];
    yy[0]=cadd(u0,u2); yy[2]=csub(u0,u2);
    if (S < 0) { yy[1]=csub(u1,iu3); yy[3]=cadd(u1,iu3); }
    else       { yy[1]=cadd(u1,iu3); yy[3]=csub(u1,iu3); }
    #pragma unroll
    for (int c0 = 0; c0 < 4; ++c0) {
      const int p = (b0*c0) & 15;
      c32 w = mkc(C16[p], (S<0) ? -S16[p] : S16[p]);
      s[c0*4 + b0] = cmul(yy[c0], w);
    }
  }
  #pragma unroll
  for (int c0 = 0; c0 < 4; ++c0) {
    c32 x0=s[c0*4+0], x1=s[c0*4+1], x2=s[c0*4+2], x3=s[c0*4+3];
    c32 u0=cadd(x0,x2), u1=csub(x0,x2), u2=cadd(x1,x3), u3=csub(x1,x3);
    c32 iu3 = mkc(-u3.y, u3.x);
    c32 yy[4];
    yy[0]=cadd(u0,u2); yy[2]=csub(u0,u2);
    if (S < 0) { yy[1]=csub(u1,iu3); yy[3]=cadd(u1,iu3); }
    else       { yy[1]=cadd(u1,iu3); yy[3]=csub(u1,iu3); }
    v[c0+0]=yy[0]; v[c0+4]=yy[1]; v[c0+8]=yy[2]; v[c0+12]=yy[3];
  }
}

// ------------- 256-pt FFT, 16-thread team, 16 KB two-phase transpose ------
template<int S>
__device__ __forceinline__ void fft256_team(c32 v[16], int r, int t, c32* sc) {
  fft16<S>(v);
  float ang = (float)S * (2.0f*PI_F/256.0f) * (float)r;
  c32 st; __sincosf(ang, &st.y, &st.x);
  c32 w = st;
  #pragma unroll
  for (int c = 1; c < 16; ++c) { v[c] = cmul(v[c], w); w = cmul(w, st); }
  int p  = r*8 + (t & 7);
  int fr = (r & 1) << 3;
  __syncthreads();
  if (t < 8) {
    #pragma unroll
    for (int c = 0; c < 16; ++c)
      sc[c*128 + (p ^ ((c & 1) << 3))] = v[c];
  }
  __syncthreads();
  if (t < 8) {
    #pragma unroll
    for (int a = 0; a < 16; ++a)
      v[a] = sc[r*128 + ((a*8 + (t & 7)) ^ fr)];
  }
  __syncthreads();
  if (t >= 8) {
    #pragma unroll
    for (int c = 0; c < 16; ++c)
      sc[c*128 + (p ^ ((c & 1) << 3))] = v[c];
  }
  __syncthreads();
  if (t >= 8) {
    #pragma unroll
    for (int a = 0; a < 16; ++a)
      v[a] = sc[r*128 + ((a*8 + (t & 7)) ^ fr)];
  }
  fft16<S>(v);
}

// ---------------- prep A: pm partial sums (md-separable) -------------------
__global__ __launch_bounds__(256) void k_pm(const float* __restrict__ hp,
                                            float* __restrict__ pm_part) {
  __shared__ float r0[256], r1[256];
  int t = threadIdx.x, b = blockIdx.x;
  int gid = b*256 + t;
  float s0 = 0.f, s1 = 0.f;
  for (int tt = gid; tt < 65537; tt += 16384) {
    int ci = (tt * 8) / 65537;
    float cs = hp[ci*4+0] + hp[ci*4+1] + hp[ci*4+2] + hp[ci*4+3];
    float ang = (6.2831853071795864769f * (float)tt) / 65537.0f;
    s0 += cs;
    s1 += cs * sinf(ang);
  }
  r0[t] = s0; r1[t] = s1;
  __syncthreads();
  for (int s = 128; s > 0; s >>= 1) {
    if (t < s) { r0[t] += r0[t+s]; r1[t] += r1[t+s]; }
    __syncthreads();
  }
  if (t == 0) { pm_part[2*b] = r0[0]; pm_part[2*b+1] = r1[0]; }
}

// ---------------- prep B: MLP md, final pm, spectral line table ------------
__global__ __launch_bounds__(256) void k_prep2(const float* __restrict__ b1,
    const float* __restrict__ W2, const float* __restrict__ b2,
    const float* __restrict__ W3, const float* __restrict__ b3,
    const float* __restrict__ fw, const float* __restrict__ pm_part,
    float* __restrict__ pm_out, int* __restrict__ hidx, float* __restrict__ amp) {
  __shared__ float r0[64], r1[64];
  __shared__ float s_pm;
  int t = threadIdx.x;
  if (t < 64) { r0[t] = pm_part[2*t]; r1[t] = pm_part[2*t+1]; }
  __syncthreads();
  if (t == 0) {
    float h1[32], h2v[16];
    for (int i=0;i<32;i++){ float z = b1[i]; h1[i] = z > 0.f ? z : 0.f; }
    for (int o=0;o<16;o++){ float acc = b2[o];
      for (int i=0;i<32;i++) acc += h1[i]*W2[i*16+o];
      h2v[o] = acc > 0.f ? acc : 0.f; }
    float md = b3[1];
    for (int i=0;i<16;i++) md += h2v[i]*W3[i*8+1];
    float S0 = 0.f, S1 = 0.f;
    for (int i=0;i<64;i++){ S0 += r0[i]; S1 += r1[i]; }
    s_pm = (S0 + md*S1) / (65537.0f * 4.0f);
    pm_out[0] = s_pm;
  }
  __syncthreads();
  if (t < 40) {
    const double SPECF[8] = {7.83, 528.0, 396.0, 2.5, 14.1, 432.0, 6.0, 30.0};
    int j = t / 5, mi = t % 5;
    double mult = (double)(mi + 1);
    double hf = SPECF[j] * mult;
    double ratio = hf * (131072.0 / 22050.0);
    hidx[t] = (int)floor(ratio + 0.5);
    amp[t] = (float)((double)fw[j] * pow(mult, -1.2) * (1.0 + (double)s_pm));
  }
}

// ---------------- gain curve, TRANSPOSED: gainT[c*256 + m] = gain[c+256m] --
__global__ __launch_bounds__(256) void k_gain(float* __restrict__ gainT,
    const float* __restrict__ bw, const int* __restrict__ hidx,
    const float* __restrict__ amp) {
  int j = blockIdx.x*256 + threadIdx.x;
  if (j > 65536) return;
  int i = (j == 65536) ? 65536 : (((j >> 8) & 255) | ((j & 255) << 8));
  float f = (float)((double)i * (22050.0/131072.0));
  float g = 1.0f;
  constexpr double LO[6] = {1,4,8,13,30,100};
  constexpr double HI[6] = {4,8,13,30,100,200};
  #pragma unroll
  for (int k = 0; k < 6; ++k) {
    float center = (float)(0.5*(LO[k]+HI[k]));
    float sig    = (float)(0.25*(HI[k]-LO[k]));
    float dm = (f - center)/sig;
    float mask = expf(-0.5f*dm*dm);
    if (f < (float)LO[k] || f > (float)HI[k]) mask = 0.f;
    float ang = (float)(6.283185307179586*0.5*(LO[k]+HI[k])) * (float)i / 22050.0f;
    g *= 1.0f + mask * bw[k] * (1.0f + 0.2f*sinf(ang));
  }
  for (int l = 0; l < 40; ++l) {
    int d = i - hidx[l];
    if (d >= -15 && d <= 15) {
      float dd = (float)d * 0.2f;
      g *= 1.0f + amp[l] * expf(-0.5f*dd*dd);
    }
  }
  gainT[j] = g;
}

// ---------------- forward pass 1: pack + column FFT + 4-step twiddle ------
__global__ __launch_bounds__(256, 4) void k_fwd1(const float* __restrict__ x,
                                                 h2* __restrict__ A, int s0) {
  __shared__ float smem[4096];       // 16 KB
  c32* sc = (c32*)smem;
  h2*  stg = (h2*)smem;
  int b = blockIdx.x; int sl = b >> 4; int g = b & 15;
  int t = threadIdx.x & 15, r = threadIdx.x >> 4;
  int n1 = g*16 + t;
  const float* xb = x + (size_t)(s0 + sl) * L_SIG;
  c32 v[16];
  #pragma unroll
  for (int j = 0; j < 16; ++j) {
    int n = n1 + 256*r + 4096*j;
    c32 z = mkc(0.f, 0.f);
    if (n < 32768)       { z.x = xb[2*n]; z.y = xb[2*n+1]; }
    else if (n == 32768) { z.x = xb[65536]; }
    v[j] = z;
  }
  fft256_team<-1>(v, r, t, sc);
  float a0 = -(2.0f*PI_F/65536.0f) * (float)(n1 * r);
  float a1 = -(2.0f*PI_F/4096.0f)  * (float)n1;
  c32 wb, wst;
  __sincosf(a0, &wb.y, &wb.x);
  __sincosf(a1, &wst.y, &wst.x);
  #pragma unroll
  for (int j = 0; j < 16; ++j) { v[j] = cmul(v[j], wb); wb = cmul(wb, wst); }
  __syncthreads();
  #pragma unroll
  for (int j = 0; j < 16; ++j)
    stg[(r + 16*j)*16 + t] = c2h(v[j]);
  __syncthreads();
  h2* Ab = A + (size_t)sl * NH;
  int u = threadIdx.x & 15, k2b = threadIdx.x >> 4;
  #pragma unroll
  for (int m = 0; m < 16; ++m) {
    int k2 = k2b + 16*m;
    Ab[(size_t)k2*256 + g*16 + u] = stg[k2*16 + u];
  }
}

// ---------------- forward pass 2: row FFT -> ZT[k2*256 + k1] (coalesced) --
__global__ __launch_bounds__(256, 4) void k_fwd2(const h2* __restrict__ A,
                                                 h2* __restrict__ ZT) {
  __shared__ float smem[4160];       // 16.6 KB: stg-in / sc / stg-out (aliased)
  c32* sc = (c32*)smem;
  h2* stg = (h2*)smem;
  int b = blockIdx.x; int sl = b >> 4; int g = b & 15;
  int tid = threadIdx.x;
  int t = tid & 15, r = tid >> 4;
  const h2* Ab = A + (size_t)sl * NH;
  #pragma unroll
  for (int m = 0; m < 4; ++m) {
    int flat = tid + 256*m;
    int row = flat >> 6, i = flat & 63;
    float4 z = ((const float4*)(Ab + (size_t)(g*16 + row)*256))[i];
    *((float4*)&stg[row*260 + 4*i]) = z;
  }
  __syncthreads();
  c32 v[16];
  #pragma unroll
  for (int j = 0; j < 16; ++j)
    v[j] = h2c(stg[t*260 + r + 16*j]);     // row k2=g16+t, FFT over n1 -> k1
  fft256_team<-1>(v, r, t, sc);
  __syncthreads();                         // drain fft sc reads
  #pragma unroll
  for (int j = 0; j < 16; ++j)
    stg[t*260 + r + 16*j] = c2h(v[j]);     // [k2local][k1], 2-way banks
  __syncthreads();
  h2* Zb = ZT + (size_t)sl * NH;
  #pragma unroll
  for (int w = 0; w < 4; ++w) {
    int flat = tid + 256*w;
    int k2l = flat >> 6, i = flat & 63;
    *((float4*)(Zb + (size_t)(g*16 + k2l)*256 + 4*i)) =
        *((const float4*)(stg + k2l*260 + 4*i));
  }
}

// ---------------- fused mid + inv1, 16 CONSECUTIVE output rows -------------
// ZT layout: ZT[(k&255)*256 + (k>>8)]. Block (sl,g) produces Z' bins with
// k&255 in [16g,16g+16): per thread m, an 18-step sliding window over bins
// K0..K0+17 (K0 = 16g-1+256m). Each pairupG yields BOTH sides (Uk,mk) and
// (UK,mK); output Z'[k] combines smoothed Xc[k] (mk neighbors) and smoothed
// Xc[NH-k] (mK neighbors, since mirror-of-(k+-1) = (NH-k)-+1). No mirror
// writes -> inverse FFT + store is verbatim round-4 inv1 (contiguous 64B).
struct UP { c32 Uk, UK; float mk, mK, cn, sn; };
__device__ __forceinline__ UP pairupG(const h2* __restrict__ Zs, int k,
                                      const float* __restrict__ gT) {
  UP u;
  int kk = k & (NH-1);
  int Km = (NH - k) & (NH-1);
  int ik = ((kk & 255) << 8) | (kk >> 8);
  int ib = ((Km & 255) << 8) | (Km >> 8);
  c32 zk = h2c(Zs[ik]);
  c32 zb = h2c(Zs[ib]);
  c32 Aa = mkc(0.5f*(zk.x + zb.x), 0.5f*(zk.y - zb.y));
  c32 Bm = mkc(0.5f*(zk.x - zb.x), 0.5f*(zk.y + zb.y));
  __sincosf((PI_F/65536.0f)*(float)k, &u.sn, &u.cn);
  c32 wB = cmul(mkc(-u.sn, -u.cn), Bm);
  float gk = (k >= NH) ? gT[NH] : gT[ik];   // halo pairup k==NH: gain[65536]
  int K2 = NH - k;
  float gK = (K2 >= NH) ? gT[NH] : gT[ib];
  c32 Xk = mkc((Aa.x + wB.x)*gk,  (Aa.y + wB.y)*gk);
  c32 XK = mkc((Aa.x - wB.x)*gK, -(Aa.y - wB.y)*gK);
  float nk = Xk.x*Xk.x + Xk.y*Xk.y;
  float nK = XK.x*XK.x + XK.y*XK.y;
  float rk = rsqrtf(nk), rK = rsqrtf(nK);
  bool kv = (k >= 0);
  u.Uk = (nk > 0.f) ? mkc(Xk.x*rk, Xk.y*rk) : mkc(1.f, 0.f);
  u.UK = (nK > 0.f) ? mkc(XK.x*rK, XK.y*rK) : mkc(1.f, 0.f);
  u.mk = (kv && nk > 0.f) ? nk*rk : 0.f;
  u.mK = (kv && nK > 0.f) ? nK*rK : 0.f;
  return u;
}

__global__ __launch_bounds__(256, 4) void k_mi(const h2* __restrict__ ZT,
                                               h2* __restrict__ B,
                                               const float* __restrict__ gT) {
  __shared__ float smem[4160];          // 16x260 h2 rows (16.6 KB); sc/stg alias
  h2*  rowsO = (h2*)smem;
  c32* sc    = (c32*)smem;
  h2*  stg   = (h2*)smem;
  int b = blockIdx.x; int sl = b >> 4; int g = b & 15;
  int tid = threadIdx.x; int t = tid & 15; int r = tid >> 4;
  const h2* Zs = ZT + (size_t)sl * NH;
  h2* Bb = B + (size_t)sl * NH;
  int m = tid;
  int K0 = 16*g - 1 + 256*m;
  // ---- mid: sliding window, outputs bins K0+1 .. K0+16 (o1 only) --------
  h2 o1[16];
  float m1a=0.f, m1b=0.f, m2a=0.f, m2b=0.f, cnp=0.f, snp=0.f;
  c32 u1p = mkc(1.f,0.f), u2p = mkc(1.f,0.f);
  const float invN = 1.0f/65536.0f;
  #pragma unroll
  for (int s = 0; s <= 17; ++s) {
    UP u = pairupG(Zs, K0 + s, gT);
    if (s >= 2) {
      int kq = K0 + s - 1;
      float msm = (kq == 0) ? m1b : 0.7f*m1b + 0.15f*(m1a + u.mk);
      float msh = (kq == 0) ? m2b : 0.7f*m2b + 0.15f*(m2a + u.mK);
      c32 XcL = mkc(u1p.x*msm, u1p.y*msm);
      c32 XcH = mkc(u2p.x*msh, u2p.y*msh);
      c32 E = mkc(0.5f*(XcL.x + XcH.x), 0.5f*(XcL.y - XcH.y));
      c32 D = mkc(0.5f*(XcL.x - XcH.x), 0.5f*(XcL.y + XcH.y));
      c32 O = cmul(mkc(cnp, snp), D);
      o1[s-2] = c2h(mkc((E.x - O.y)*invN, (E.y + O.x)*invN));
    }
    m1a = m1b; m1b = u.mk; m2a = m2b; m2b = u.mK;
    u1p = u.Uk; u2p = u.UK; cnp = u.cn; snp = u.sn;
  }
  // ---- exchange: slot s = local row s (= k2 row 16g+s), col m ------------
  #pragma unroll
  for (int s = 0; s < 16; ++s)
    rowsO[s*260 + m] = o1[s];
  __syncthreads();
  // ---- inverse column FFT + twiddle + store (verbatim round-4 inv1) -----
  int a = g*16 + t;
  c32 v[16];
  #pragma unroll
  for (int j = 0; j < 16; ++j) v[j] = h2c(rowsO[t*260 + r + 16*j]);
  fft256_team<1>(v, r, t, sc);
  float a0 = (2.0f*PI_F/65536.0f) * (float)(a * r);
  float a1 = (2.0f*PI_F/4096.0f)  * (float)a;
  c32 wb, wst;
  __sincosf(a0, &wb.y, &wb.x);
  __sincosf(a1, &wst.y, &wst.x);
  #pragma unroll
  for (int j = 0; j < 16; ++j) { v[j] = cmul(v[j], wb); wb = cmul(wb, wst); }
  __syncthreads();
  #pragma unroll
  for (int j = 0; j < 16; ++j)
    stg[(r + 16*j)*16 + t] = c2h(v[j]);
  __syncthreads();
  int u = tid & 15, m2b_ = tid >> 4;
  #pragma unroll
  for (int q = 0; q < 16; ++q) {
    int m2 = m2b_ + 16*q;
    Bb[(size_t)m2*256 + g*16 + u] = stg[m2*16 + u];
  }
}

// ---------------- inverse pass 2: row FFT (+) -> real output --------------
__global__ __launch_bounds__(256, 4) void k_inv2(const h2* __restrict__ B,
                                                 float* __restrict__ out, int s0) {
  __shared__ float smem[4160];
  c32* sc = (c32*)smem;
  h2* stg = (h2*)smem;
  int b = blockIdx.x; int sl = b >> 4; int g = b & 15;
  int tid = threadIdx.x;
  int t = tid & 15, r = tid >> 4;
  const h2* Bb = B + (size_t)sl * NH;
  #pragma unroll
  for (int m = 0; m < 4; ++m) {
    int flat = tid + 256*m;
    int row = flat >> 6, i = flat & 63;
    float4 z = ((const float4*)(Bb + (size_t)(g*16 + row)*256))[i];
    *((float4*)&stg[row*260 + 4*i]) = z;
  }
  __syncthreads();
  c32 v[16];
  #pragma unroll
  for (int j = 0; j < 16; ++j)
    v[j] = h2c(stg[t*260 + r + 16*j]);
  fft256_team<1>(v, r, t, sc);
  float* yb = out + (size_t)(s0 + sl) * L_SIG;
  int m2 = g*16 + t;
  #pragma unroll
  for (int j = 0; j < 16; ++j) {
    int m1 = r + 16*j;
    if (m1 <= 127) {
      int m = m2 + 256*m1;
      yb[2*m]   = v[j].x;
      yb[2*m+1] = v[j].y;
    } else if (m1 == 128 && m2 == 0) {
      yb[65536] = v[j].x;
    }
  }
}

// --------------------------------------------------------------------------
extern "C" void kernel_launch(void* const* d_in, const int* in_sizes, int n_in,
                              void* d_out, int out_size, void* d_ws, size_t ws_size,
                              hipStream_t stream) {
  const float* x  = (const float*)d_in[0];
  const float* bw = (const float*)d_in[1];
  const float* fw = (const float*)d_in[2];
  const float* hp = (const float*)d_in[3];
  // d_in[4] = W1: mathematically unused (tn==0 at the only sampled row)
  const float* b1 = (const float*)d_in[5];
  const float* W2 = (const float*)d_in[6];
  const float* b2 = (const float*)d_in[7];
  const float* W3 = (const float*)d_in[8];
  const float* b3 = (const float*)d_in[9];
  float* out = (float*)d_out;
  char* ws = (char*)d_ws;

  const size_t perSig = (size_t)NH * sizeof(h2);              // 256 KiB / signal / buffer
  const size_t tail   = (size_t)L_SIG * sizeof(float) + 2048; // gainT + scalars + pm_part
  size_t cap = (ws_size > tail) ? (ws_size - tail) / (2*perSig) : 1;
  int chunk = (cap >= (size_t)NSIG) ? NSIG : (cap < 1 ? 1 : (int)cap);

  h2*    A     = (h2*)ws;
  h2*    Bb    = (h2*)(ws + (size_t)chunk*perSig);
  float* gainT = (float*)(ws + 2*(size_t)chunk*perSig);
  float* pm    = gainT + L_SIG;
  int*   hidx  = (int*)(pm + 1);
  float* amp   = (float*)(hidx + 40);
  float* pm_part = amp + 40;          // 128 floats

  k_pm   <<<64, 256, 0, stream>>>(hp, pm_part);
  k_prep2<<<1,  256, 0, stream>>>(b1, W2, b2, W3, b3, fw, pm_part, pm, hidx, amp);
  k_gain <<<257,256, 0, stream>>>(gainT, bw, hidx, amp);

  for (int s0 = 0; s0 < NSIG; s0 += chunk) {
    int S = (NSIG - s0 < chunk) ? (NSIG - s0) : chunk;
    k_fwd1<<<S*16, 256, 0, stream>>>(x, A, s0);
    k_fwd2<<<S*16, 256, 0, stream>>>(A, Bb);        // -> ZT (transposed)
    k_mi  <<<S*16, 256, 0, stream>>>(Bb, A, gainT); // mid + inv1 -> B (m2-major)
    k_inv2<<<S*16, 256, 0, stream>>>(A, out, s0);
  }
}